// Round 6
// baseline (118.061 us; speedup 1.0000x reference)
//
#include <hip/hip_runtime.h>

// Block-factorized depthwise 7x7 conv, per-(n,c,8x8-block) filters.
// feat: [N=2, C=128, H=256, W=256] f32 (NCHW)
// filters_lr: [N, C*49, 32, 32] f32 ; weight[n,hb,wb,c,t] = filt[n, c*49+t, hb, wb]
// out[n,c,h,w] = sum_t feat[n,c,h+dh-3,w+dw-3] * weight[n,h/8,w/8,c,t], t=dh*7+dw
//
// NO LDS, NO barrier (round-5 structure, spill-proofed):
//  - __launch_bounds__(256,1): VGPR cap 256 (round 5's (256,2) capped at 128
//    -> 30 hoisted float4 loads + 49 wt + 16 acc spilled ~30MB to scratch).
//  - Rolling weight loads: tap-row t issued 2 iters before first use, dead 4
//    later -> <=42 live weight VGPRs instead of 49 pinned from kernel top.
//  - Single-depth input prefetch (row jj+1 loads while row jj FMAs) instead of
//    a fully hoisted 30-load block.
// Thread = 4 rows x 4 cols; win built from 3 aligned float4 (L/M/R); L1/L2
// absorb the 3x line re-read (HBM unique bytes unchanged). Lane/row edges via
// predicated zero4 (verified: lane63 R = cols 256..258 -> zero; win[0],win[11]
// unused).

__global__ __launch_bounds__(256, 1)
void block_fac_kernel(const float* __restrict__ feat,
                      const float* __restrict__ filt,
                      float* __restrict__ out) {
    const int bid = blockIdx.x;           // n*128*16 + c*16 + hb2
    const int hb2 = bid & 15;
    const int c   = (bid >> 4) & 127;
    const int n   = bid >> 11;
    const int tid = threadIdx.x;

    const int lane = tid & 63;
    const int wave = tid >> 6;
    const int c0   = lane << 2;           // output col base (0..252)
    const int wb   = lane >> 1;           // weight block col (0..31)
    const int r0   = wave << 2;           // output row base in tile (0,4,8,12)
    const int hb   = hb2 * 2 + (wave >> 1);  // weight block row

    const int H0 = hb2 * 16;              // first output row of the tile
    const float* fbase  = feat + (size_t)(n * 128 + c) * (256 * 256);
    const float* wgbase = filt + (size_t)((n * 128 + c) * 49) * 1024 + hb * 32 + wb;

    const bool okL = (c0 >= 4);
    const bool okR = (c0 <= 248);
    const float4 z4 = make_float4(0.f, 0.f, 0.f, 0.f);

    // ---- rolling weight file: prologue loads tap-rows 0,1
    float wt[49];
    #pragma unroll
    for (int t = 0; t < 14; ++t) wt[t] = wgbase[(size_t)t * 1024];

    // ---- input row prefetch (row index jj within r0-3 .. r0+6)
    float4 nL = z4, nM = z4, nR = z4;
    {
        const int gr = H0 + r0 - 3;       // wave-uniform
        if (gr >= 0) {                    // gr < 256 always here
            const float* rp = fbase + (size_t)gr * 256 + c0;
            nM = *(const float4*)(rp);
            nL = okL ? *(const float4*)(rp - 4) : z4;
            nR = okR ? *(const float4*)(rp + 4) : z4;
        }
    }

    float acc[4][4] = {};

    #pragma unroll
    for (int jj = 0; jj < 10; ++jj) {     // input row (H0+r0-3)+jj ; out row a: dh=jj-a
        float4 L = nL, M = nM, R = nR;
        if (jj < 9) {                     // prefetch next row
            const int gr = H0 + r0 - 3 + (jj + 1);
            nL = z4; nM = z4; nR = z4;
            if (gr >= 0 && gr < 256) {
                const float* rp = fbase + (size_t)gr * 256 + c0;
                nM = *(const float4*)(rp);
                nL = okL ? *(const float4*)(rp - 4) : z4;
                nR = okR ? *(const float4*)(rp + 4) : z4;
            }
        }
        if (jj + 2 <= 6) {                // rolling weight load, 2-iter lead
            #pragma unroll
            for (int dw = 0; dw < 7; ++dw)
                wt[(jj + 2) * 7 + dw] = wgbase[(size_t)((jj + 2) * 7 + dw) * 1024];
        }
        float win[12] = {L.x, L.y, L.z, L.w,
                         M.x, M.y, M.z, M.w,
                         R.x, R.y, R.z, R.w};
        #pragma unroll
        for (int a = 0; a < 4; ++a) {
            int dh = jj - a;
            if (dh >= 0 && dh <= 6) {
                #pragma unroll
                for (int dw = 0; dw < 7; ++dw) {
                    float wv = wt[dh * 7 + dw];
                    #pragma unroll
                    for (int i = 0; i < 4; ++i)
                        acc[a][i] += win[i + dw + 1] * wv;   // col c0+i+dw-3
                }
            }
        }
    }

    float* obase = out + (size_t)((n * 128 + c) * 256 + H0 + r0) * 256 + c0;
    #pragma unroll
    for (int a = 0; a < 4; ++a)
        *(float4*)(obase + (size_t)(a * 256)) =
            make_float4(acc[a][0], acc[a][1], acc[a][2], acc[a][3]);
}

extern "C" void kernel_launch(void* const* d_in, const int* in_sizes, int n_in,
                              void* d_out, int out_size, void* d_ws, size_t ws_size,
                              hipStream_t stream) {
    const float* feat = (const float*)d_in[0];
    const float* filt = (const float*)d_in[1];
    float* out = (float*)d_out;
    dim3 grid(2 * 128 * 16);
    dim3 block(256);
    hipLaunchKernelGGL(block_fac_kernel, grid, block, 0, stream, feat, filt, out);
}

// Round 7
// 117.436 us; speedup vs baseline: 1.0053x; 1.0053x over previous
//
#include <hip/hip_runtime.h>

// Block-factorized depthwise 7x7 conv, per-(n,c,8x8-block) filters.
// feat: [N=2, C=128, H=256, W=256] f32 (NCHW)
// filters_lr: [N, C*49, 32, 32] f32 ; weight[n,hb,wb,c,t] = filt[n, c*49+t, hb, wb]
// out[n,c,h,w] = sum_t feat[n,c,h+dh-3,w+dw-3] * weight[n,h/8,w/8,c,t], t=dh*7+dw
//
// NO LDS, NO barrier. Block = 256 threads = 16 output rows x 256 cols.
// Thread = 4 rows x 4 cols: 49 weights + 30 input float4 loads, ALL hoisted by
// the compiler into one deep independent load queue (ILP latency hiding), then
// straight-line FMAs. Round-5 structure; the only change vs r5 is
// __launch_bounds__(256,1): VGPR cap 256 instead of 128. ~205 live VGPRs fit
// (r5 spilled 30MB at the 128 cap; r6's just-in-time loads serialized on
// in-order vmcnt). LDS window reads are NOT used anywhere: 16B/lane-stride
// ds_read has an unavoidable 4-way bank conflict (constant 1.112e7 counter in
// r2-r4).

__global__ __launch_bounds__(256, 1)
void block_fac_kernel(const float* __restrict__ feat,
                      const float* __restrict__ filt,
                      float* __restrict__ out) {
    const int bid = blockIdx.x;           // n*128*16 + c*16 + hb2
    const int hb2 = bid & 15;
    const int c   = (bid >> 4) & 127;
    const int n   = bid >> 11;
    const int tid = threadIdx.x;

    const int lane = tid & 63;
    const int wave = tid >> 6;
    const int c0   = lane << 2;           // output col base (0..252)
    const int wb   = lane >> 1;           // weight block col (0..31)
    const int r0   = wave << 2;           // output row base in tile (0,4,8,12)
    const int hb   = hb2 * 2 + (wave >> 1);  // weight block row

    // ---- weights: global -> VGPR, one coalesced 128B line per tap per wave
    const float* wgbase = filt + (size_t)((n * 128 + c) * 49) * 1024 + hb * 32 + wb;
    float wt[49];
    #pragma unroll
    for (int t = 0; t < 49; ++t) wt[t] = wgbase[(size_t)t * 1024];

    const int H0 = hb2 * 16;              // first output row of the tile
    const float* fbase = feat + (size_t)(n * 128 + c) * (256 * 256);

    const bool okL = (c0 >= 4);           // lane 0 left edge
    const bool okR = (c0 <= 248);         // lane 63 right edge
    const float4 z4 = make_float4(0.f, 0.f, 0.f, 0.f);

    float acc[4][4] = {};

    #pragma unroll
    for (int jj = 0; jj < 10; ++jj) {     // input row (H0+r0-3)+jj ; out row a uses dh=jj-a
        const int gr = H0 + r0 - 3 + jj;  // wave-uniform
        float4 L = z4, M = z4, R = z4;
        if (gr >= 0 && gr < 256) {        // uniform branch
            const float* rp = fbase + (size_t)gr * 256 + c0;
            M = *(const float4*)(rp);
            L = okL ? *(const float4*)(rp - 4) : z4;
            R = okR ? *(const float4*)(rp + 4) : z4;
        }
        // win[k] = feat col c0 + k - 4  (zeros outside [0,256))
        float win[12] = {L.x, L.y, L.z, L.w,
                         M.x, M.y, M.z, M.w,
                         R.x, R.y, R.z, R.w};
        #pragma unroll
        for (int a = 0; a < 4; ++a) {
            int dh = jj - a;
            if (dh >= 0 && dh <= 6) {
                #pragma unroll
                for (int dw = 0; dw < 7; ++dw) {
                    float wv = wt[dh * 7 + dw];
                    #pragma unroll
                    for (int i = 0; i < 4; ++i)
                        acc[a][i] += win[i + dw + 1] * wv;   // col c0+i+dw-3
                }
            }
        }
    }

    float* obase = out + (size_t)((n * 128 + c) * 256 + H0 + r0) * 256 + c0;
    #pragma unroll
    for (int a = 0; a < 4; ++a)
        *(float4*)(obase + (size_t)(a * 256)) =
            make_float4(acc[a][0], acc[a][1], acc[a][2], acc[a][3]);
}

extern "C" void kernel_launch(void* const* d_in, const int* in_sizes, int n_in,
                              void* d_out, int out_size, void* d_ws, size_t ws_size,
                              hipStream_t stream) {
    const float* feat = (const float*)d_in[0];
    const float* filt = (const float*)d_in[1];
    float* out = (float*)d_out;
    dim3 grid(2 * 128 * 16);
    dim3 block(256);
    hipLaunchKernelGGL(block_fac_kernel, grid, block, 0, stream, feat, filt, out);
}

// Round 8
// 42.971 us; speedup vs baseline: 2.7474x; 2.7329x over previous
//
#include <hip/hip_runtime.h>
#include <stdint.h>

// Block-factorized depthwise 7x7 conv, per-(n,c,8x8-block) filters.
// feat: [N=2, C=128, H=256, W=256] f32 (NCHW)
// filters_lr: [N, C*49, 32, 32] f32 ; weight[n,hb,wb,c,t] = filt[n, c*49+t, hb, wb]
// out[n,c,h,w] = sum_t feat[n,c,h+dh-3,w+dw-3] * weight[n,h/8,w/8,c,t], t=dh*7+dw
//
// r4 structure (best: 47.6us) scaled vertically: block = 256 threads = 32
// output rows x 256 cols; thread = 8 rows x 4 cols; wave = one full 8-row hb
// block. Per output: DS reads 1.31 b128 (vs r4 1.875), weights 49/32 outputs
// (vs 49/16), staging halo 1.19x (vs 1.375x). Staging via global_load_lds
// (16B/lane, linear dest, wave-uniform row base) so weight + tile loads drain
// concurrently at the single barrier. __launch_bounds__(256,1): no VGPR cap
// (r5: a 128 cap spilled 30MB; r6/r7: no-LDS variants latency-serialize).

#define LDW   264   // floats/LDS row: [0] slack, [1..3] zero pad, [4..259] data, [260..262] pad, [263] slack
#define NROWS 38    // 32 output rows + 6 halo

typedef const uint32_t __attribute__((address_space(1))) guint;
typedef uint32_t __attribute__((address_space(3))) luint;

__global__ __launch_bounds__(256, 1)
void block_fac_kernel(const float* __restrict__ feat,
                      const float* __restrict__ filt,
                      float* __restrict__ out) {
    __shared__ float s_in[NROWS * LDW];   // 40128 B

    const int bid = blockIdx.x;           // n*128*8 + c*8 + hb4
    const int hb4 = bid & 7;              // group of 4 vertical hb blocks
    const int c   = (bid >> 3) & 127;
    const int n   = bid >> 10;
    const int tid = threadIdx.x;

    const int lane = tid & 63;
    const int wave = tid >> 6;
    const int c0   = lane << 2;           // output col base (0..252)
    const int wb   = lane >> 1;           // weight block col (0..31)
    const int r0   = wave << 3;           // output row base in tile (0,8,16,24)
    const int hb   = hb4 * 4 + wave;      // weight block row (one per wave)

    // ---- weights: global -> VGPR, one coalesced 128B line per tap per wave;
    //      issued first, drains concurrently with the staging queue.
    const float* wgbase = filt + (size_t)((n * 128 + c) * 49) * 1024 + hb * 32 + wb;
    float wt[49];
    #pragma unroll
    for (int t = 0; t < 49; ++t) wt[t] = wgbase[(size_t)t * 1024];

    const int H0 = hb4 * 32;              // first output row of the tile
    const int h0 = H0 - 3;                // first staged input row

    // ---- zero the 3-col pads (float idx 1..3 and 260..262)
    if (tid < NROWS * 6) {
        int r = tid / 6, j = tid - r * 6;
        int p = (j < 3) ? (1 + j) : (257 + j);
        s_in[r * LDW + p] = 0.f;
    }

    // ---- stage input rows h0..h0+37 via global_load_lds (16B/lane, linear dest)
    const float* fbase = feat + (size_t)(n * 128 + c) * (256 * 256);
    for (int idx = tid; idx < NROWS * 64; idx += 256) {   // 2432 chunks
        int r  = idx >> 6;                // wave-uniform per iteration
        int gr = h0 + r;
        float* lp = &s_in[r * LDW + 4];   // wave-uniform base; HW adds lane*16
        if (gr >= 0 && gr < 256) {        // uniform branch
            const float* gp = fbase + (size_t)gr * 256 + ((idx & 63) << 2);
            __builtin_amdgcn_global_load_lds((guint*)gp, (luint*)lp, 16, 0, 0);
        } else {
            *(float4*)(&s_in[r * LDW + 4 + ((idx & 63) << 2)]) =
                make_float4(0.f, 0.f, 0.f, 0.f);
        }
    }
    __syncthreads();                      // single vmcnt(0): both streams drain together

    // ---- compute: thread -> rows H0+r0..+7, cols c0..c0+3
    float acc[8][4] = {};

    #pragma unroll
    for (int jj = 0; jj < 14; ++jj) {     // staged row r0+jj; out row a uses dh=jj-a
        const float* rp = &s_in[(r0 + jj) * LDW + c0];   // 16B aligned
        float4 a0 = *(const float4*)(rp);
        float4 a1 = *(const float4*)(rp + 4);
        float4 a2 = *(const float4*)(rp + 8);
        float win[12] = {a0.x, a0.y, a0.z, a0.w,
                         a1.x, a1.y, a1.z, a1.w,
                         a2.x, a2.y, a2.z, a2.w};
        #pragma unroll
        for (int a = 0; a < 8; ++a) {
            int dh = jj - a;
            if (dh >= 0 && dh <= 6) {
                #pragma unroll
                for (int dw = 0; dw < 7; ++dw) {
                    float wv = wt[dh * 7 + dw];
                    #pragma unroll
                    for (int i = 0; i < 4; ++i)
                        acc[a][i] += win[i + dw + 1] * wv;   // col c0+i+dw-3
                }
            }
        }
    }

    float* obase = out + (size_t)((n * 128 + c) * 256 + H0 + r0) * 256 + c0;
    #pragma unroll
    for (int a = 0; a < 8; ++a)
        *(float4*)(obase + (size_t)(a * 256)) =
            make_float4(acc[a][0], acc[a][1], acc[a][2], acc[a][3]);
}

extern "C" void kernel_launch(void* const* d_in, const int* in_sizes, int n_in,
                              void* d_out, int out_size, void* d_ws, size_t ws_size,
                              hipStream_t stream) {
    const float* feat = (const float*)d_in[0];
    const float* filt = (const float*)d_in[1];
    float* out = (float*)d_out;
    dim3 grid(2 * 128 * 8);
    dim3 block(256);
    hipLaunchKernelGGL(block_fac_kernel, grid, block, 0, stream, feat, filt, out);
}